// Round 4
// baseline (463.834 us; speedup 1.0000x reference)
//
#include <hip/hip_runtime.h>
#include <math.h>

#define NSLOPE 0.2f

__device__ __forceinline__ float2 nt_load_f2(const float2* p) {
    union { unsigned long long u; float2 f; } c;
    c.u = __builtin_nontemporal_load((const unsigned long long*)p);
    return c.f;
}
__device__ __forceinline__ void nt_store_f2(float2* p, float2 v) {
    union { float2 f; unsigned long long u; } c; c.f = v;
    __builtin_nontemporal_store(c.u, (unsigned long long*)p);
}

// ---------------- K0: zero degree counters ----------------
__global__ __launch_bounds__(256) void k0_zero(int* __restrict__ deg, int n) {
    int i = blockIdx.x * 256 + threadIdx.x;
    if (i < n) deg[i] = 0;
}

// ---------------- K1: h = feat @ W_fc, fused pp = h @ W_post + b_post ----------------
// block = 256 = 4 waves; 16 rows/block (4 rows/wave); lane = output col
__global__ __launch_bounds__(256) void k1_proj(
    const float* __restrict__ feat, const float* __restrict__ wfc,
    const float* __restrict__ wpost, const float* __restrict__ bpost,
    float* __restrict__ h, float4* __restrict__ pp, int n)
{
    __shared__ float wfc_s[128 * 64];   // 32 KB
    __shared__ float feat_s[16 * 128];  // 8 KB
    int t = threadIdx.x;
    for (int i = t; i < 128 * 64 / 4; i += 256)
        ((float4*)wfc_s)[i] = ((const float4*)wfc)[i];
    int row0 = blockIdx.x * 16;
    {
        const float4* fv = (const float4*)(feat + (long)row0 * 128);
        int lim = (n - row0) * (128 / 4);
        if (lim > 16 * 128 / 4) lim = 16 * 128 / 4;
        for (int i = t; i < lim; i += 256)
            ((float4*)feat_s)[i] = fv[i];
    }
    __syncthreads();
    int lane = t & 63, wv = t >> 6;
    const float* fr = feat_s + wv * 4 * 128;
    float acc[4] = {0.f, 0.f, 0.f, 0.f};
    #pragma unroll 2
    for (int k = 0; k < 128; k += 4) {
        // 4 weight cols for this lane (stride-64: 2-way alias, free)
        float w0 = wfc_s[(k + 0) * 64 + lane];
        float w1 = wfc_s[(k + 1) * 64 + lane];
        float w2 = wfc_s[(k + 2) * 64 + lane];
        float w3 = wfc_s[(k + 3) * 64 + lane];
        #pragma unroll
        for (int r = 0; r < 4; r++) {
            float4 f = *(const float4*)(fr + r * 128 + k);  // b128 broadcast
            acc[r] += f.x * w0 + f.y * w1 + f.z * w2 + f.w * w3;
        }
    }
    int r0 = row0 + wv * 4;
    #pragma unroll
    for (int r = 0; r < 4; r++)
        if (r0 + r < n) h[(long)(r0 + r) * 64 + lane] = acc[r];
    // pp epilogue: wave-wide reduction, lane = h-column
    float4 wp = ((const float4*)wpost)[lane];
    float4 bp = *((const float4*)bpost);
    #pragma unroll
    for (int r = 0; r < 4; r++) {
        float cx = acc[r] * wp.x, cy = acc[r] * wp.y,
              cz = acc[r] * wp.z, cw = acc[r] * wp.w;
        #pragma unroll
        for (int off = 32; off > 0; off >>= 1) {
            cx += __shfl_down(cx, off);
            cy += __shfl_down(cy, off);
            cz += __shfl_down(cz, off);
            cw += __shfl_down(cw, off);
        }
        if (lane == 0 && r0 + r < n) {
            float4 o;
            o.x = cx + bp.x; o.y = cy + bp.y; o.z = cz + bp.z; o.w = cw + bp.w;
            pp[r0 + r] = o;
        }
    }
}

// ---------------- K2: fused degree histogram + edge value (coalesced write) ----------------
__global__ __launch_bounds__(256) void k2_edge(
    const int* __restrict__ src, const int* __restrict__ dst,
    const float* __restrict__ noise, const float4* __restrict__ pp,
    int* __restrict__ deg, float* __restrict__ ew, int E)
{
    int e = blockIdx.x * 256 + threadIdx.x;
    if (e >= E) return;
    int s = src[e], d = dst[e];
    atomicAdd(&deg[d], 1);
    float4 ps = pp[s], pd = pp[d];               // random 16B, pp L2-resident (1.6 MB)
    float loc = ps.x + pd.y;                     // loc_l[src] + loc_r[dst]
    loc = loc >= 0.f ? loc : NSLOPE * loc;       // leaky relu
    float ev = loc + __expf(ps.z + pd.w) * noise[e];
    ew[e] = ev;                                  // coalesced
}

// ---------------- scan: exclusive prefix of deg -> base; cursor preloaded ----------------
__global__ __launch_bounds__(256) void scan_a(const int* __restrict__ deg,
                                              int* __restrict__ base,
                                              int* __restrict__ bsum, int N) {
    __shared__ int lds[256];
    int t = threadIdx.x;
    int i0 = blockIdx.x * 1024 + t * 4;
    int d0 = (i0 + 0 < N) ? deg[i0 + 0] : 0;
    int d1 = (i0 + 1 < N) ? deg[i0 + 1] : 0;
    int d2 = (i0 + 2 < N) ? deg[i0 + 2] : 0;
    int d3 = (i0 + 3 < N) ? deg[i0 + 3] : 0;
    lds[t] = d0 + d1 + d2 + d3;
    __syncthreads();
    for (int off = 1; off < 256; off <<= 1) {
        int v = (t >= off) ? lds[t - off] : 0;
        __syncthreads();
        lds[t] += v;
        __syncthreads();
    }
    int excl = t ? lds[t - 1] : 0;
    if (t == 255) bsum[blockIdx.x] = lds[255];
    if (i0 + 0 < N) base[i0 + 0] = excl;
    if (i0 + 1 < N) base[i0 + 1] = excl + d0;
    if (i0 + 2 < N) base[i0 + 2] = excl + d0 + d1;
    if (i0 + 3 < N) base[i0 + 3] = excl + d0 + d1 + d2;
}

__global__ __launch_bounds__(256) void scan_b(int* __restrict__ bsum, int nb) {
    __shared__ int lds[1024];
    int t = threadIdx.x;
    for (int i = t; i < nb; i += 256) lds[i] = bsum[i];
    __syncthreads();
    if (t == 0) {
        int run = 0;
        for (int i = 0; i < nb; i++) { int v = lds[i]; lds[i] = run; run += v; }
    }
    __syncthreads();
    for (int i = t; i < nb; i += 256) bsum[i] = lds[i];
}

// finalize base, preload scatter cursor (deg reused) with base
__global__ __launch_bounds__(256) void scan_c(int* __restrict__ base,
                                              const int* __restrict__ bsum,
                                              int* __restrict__ cur, int N, int E) {
    int i = blockIdx.x * 256 + threadIdx.x;
    if (i < N) {
        int b = base[i] + bsum[i >> 10];
        base[i] = b;
        cur[i] = b;                  // cursor starts at segment base
    } else if (i == N) base[N] = E;
}

// ---------------- K4: pure permute — one 8B scattered store per edge ----------------
__global__ __launch_bounds__(256) void k4_scatter(
    const int* __restrict__ src, const int* __restrict__ dst,
    const float* __restrict__ ew, int* __restrict__ cur,
    float2* __restrict__ ed, int E)
{
    int e = blockIdx.x * 256 + threadIdx.x;
    if (e >= E) return;
    int d = dst[e];
    float2 v; v.x = ew[e]; v.y = __int_as_float(src[e]);
    int pos = atomicAdd(&cur[d], 1);             // chain: dst -> atomic -> store
    nt_store_f2(&ed[pos], v);                    // streaming scatter, no L2 allocate
}

// ---------------- K5: one wave per node, online softmax, 4 edges in flight ----------------
__global__ __launch_bounds__(256) void k5_node(
    const int* __restrict__ base, const float2* __restrict__ ed,
    const float* __restrict__ h, const float* __restrict__ bias,
    float* __restrict__ out, int N)
{
    int wid = (int)((blockIdx.x * 256 + threadIdx.x) >> 6);
    int lane = threadIdx.x & 63;
    if (wid >= N) return;
    int b0 = base[wid], b1 = base[wid + 1];
    float bl = bias[lane];
    long ob = (long)wid * 64 + lane;
    if (b1 == b0) { out[ob] = bl; return; }
    float m = -INFINITY, acc = 0.f, ssum = 0.f;
    int j = b0;
    for (; j + 4 <= b1; j += 4) {
        float2 e0 = nt_load_f2(&ed[j]),     e1 = nt_load_f2(&ed[j + 1]),
               e2 = nt_load_f2(&ed[j + 2]), e3 = nt_load_f2(&ed[j + 3]);
        // 4 independent 256B row gathers in flight
        float v0 = h[(long)__float_as_int(e0.y) * 64 + lane];
        float v1 = h[(long)__float_as_int(e1.y) * 64 + lane];
        float v2 = h[(long)__float_as_int(e2.y) * 64 + lane];
        float v3 = h[(long)__float_as_int(e3.y) * 64 + lane];
        float mx = fmaxf(fmaxf(fmaxf(e0.x, e1.x), fmaxf(e2.x, e3.x)), m);
        float alpha = __expf(m - mx);             // first iter: exp(-inf)=0
        float w0 = __expf(e0.x - mx), w1 = __expf(e1.x - mx),
              w2 = __expf(e2.x - mx), w3 = __expf(e3.x - mx);
        ssum = ssum * alpha + ((w0 + w1) + (w2 + w3));
        acc  = acc  * alpha + (w0 * v0 + w1 * v1) + (w2 * v2 + w3 * v3);
        m = mx;
    }
    for (; j < b1; j++) {
        float2 e = nt_load_f2(&ed[j]);
        float v = h[(long)__float_as_int(e.y) * 64 + lane];
        float mx = fmaxf(m, e.x);
        float alpha = __expf(m - mx);
        float w = __expf(e.x - mx);
        ssum = ssum * alpha + w;
        acc  = acc  * alpha + w * v;
        m = mx;
    }
    out[ob] = acc / ssum + bl;
}

extern "C" void kernel_launch(void* const* d_in, const int* in_sizes, int n_in,
                              void* d_out, int out_size, void* d_ws, size_t ws_size,
                              hipStream_t stream) {
    const float* feat  = (const float*)d_in[0];
    const float* wfc   = (const float*)d_in[1];
    const float* wpost = (const float*)d_in[2];
    const float* bpost = (const float*)d_in[3];
    const float* bias  = (const float*)d_in[4];
    const float* noise = (const float*)d_in[5];
    const int*   src   = (const int*)d_in[6];
    const int*   dst   = (const int*)d_in[7];
    int N = in_sizes[0] / 128;
    int E = in_sizes[6];
    float* out = (float*)d_out;

    // ws layout (4B units), ed first for 8B alignment:
    // ed[2E] | ew[E] | h[N*64] | pp[N*4] | deg/cur[N] | base[N+1] | bsum[1024]
    float*  ws   = (float*)d_ws;
    float2* ed   = (float2*)ws;
    float*  ew   = ws + (size_t)2 * E;
    float*  h    = ew + E;
    float4* pp   = (float4*)(h + (size_t)N * 64);
    int*    deg  = (int*)(h + (size_t)N * 64 + (size_t)N * 4);
    int*    base = deg + N;
    int*    bsum = base + (N + 1);

    int nb = (N + 1023) / 1024;

    hipLaunchKernelGGL(k0_zero, dim3((N + 255) / 256), dim3(256), 0, stream, deg, N);
    hipLaunchKernelGGL(k1_proj, dim3((N + 15) / 16), dim3(256), 0, stream,
                       feat, wfc, wpost, bpost, h, pp, N);
    hipLaunchKernelGGL(k2_edge, dim3((E + 255) / 256), dim3(256), 0, stream,
                       src, dst, noise, pp, deg, ew, E);
    hipLaunchKernelGGL(scan_a, dim3(nb), dim3(256), 0, stream, deg, base, bsum, N);
    hipLaunchKernelGGL(scan_b, dim3(1), dim3(256), 0, stream, bsum, nb);
    hipLaunchKernelGGL(scan_c, dim3((N + 256) / 256), dim3(256), 0, stream,
                       base, bsum, deg, N, E);
    hipLaunchKernelGGL(k4_scatter, dim3((E + 255) / 256), dim3(256), 0, stream,
                       src, dst, ew, deg, ed, E);
    long k5_threads = (long)N * 64;
    hipLaunchKernelGGL(k5_node, dim3((unsigned)((k5_threads + 255) / 256)), dim3(256), 0, stream,
                       base, ed, h, bias, out, N);
}